// Round 11
// baseline (26.985 us; speedup 1.0000x reference)
//
#include <hip/hip_runtime.h>

// CTC batch cost (Keras, blank=C-1). B=1024, T=256, C=128, L=48, S=97.
// R11: 3 waves/block = 2 producers + 1 consumer (per batch element).
//   producers: each owns half of every 16-row chunk; dwordx4 (16B/lane)
//     linear loads, triple-buffered 3 chunks ahead, ds_write_b128 into a
//     4-slot LDS ring (linear, conflict-free), s_barrier handshake.
//   consumer: DP per row from LDS (label col + blank col). Numerics = R8-R10.
// Ring safety: slot c%4 rewritten between barriers c+3/c+4; consumer read
// of slot c finishes before its barrier c+1. Margin >= 2 barriers.

#define TT 256
#define CC 128
#define LL 48
#define CH 16          // rows per chunk
#define NC (TT / CH)   // 16 chunks

typedef float f32x4 __attribute__((ext_vector_type(4)));

template<int CTRL>
__device__ __forceinline__ float dpp_mv(float x) {
    union { float f; int i; } u, r;
    u.f = x;
    r.i = __builtin_amdgcn_update_dpp(0, u.i, CTRL, 0xF, 0xF, false); // invalid lanes -> 0
    return r.f;
}
__device__ __forceinline__ float rdlane(float x, int l) {
    union { float f; int i; } u, r;
    u.f = x;
    r.i = __builtin_amdgcn_readlane(u.i, l);
    return r.f;
}

__global__ __launch_bounds__(192) void ctc_fwd_v11(
    const float* __restrict__ y,       // [B, T, C]
    const int* __restrict__ labels,    // [B, L]
    float* __restrict__ out)           // [B]
{
    __shared__ float ring[4][CH * CC];         // 4 x 8 KB = 32 KB
    const int lane = threadIdx.x & 63;
    const int w = threadIdx.x >> 6;            // 0 = consumer, 1/2 = producers
    const int b = blockIdx.x;
    const float EPS = 1e-7f;

    if (w != 0) {
        // ---------------- producers (w = 1, 2) ----------------
        // Chunk = 16 rows = 8192 B = 8 wave-wide dwordx4 ops; producer w owns
        // j = (w-1)*4 .. (w-1)*4+3 (rows (w-1)*8 .. (w-1)*8+7).
        const f32x4* p4 = (const f32x4*)(y + (size_t)b * TT * CC);
        const int jb = (w - 1) * 4;
        f32x4 RA[4], RB[4], RC[4];

#define LOADP(set, c_) do {                                               \
    _Pragma("unroll")                                                     \
    for (int _jj = 0; _jj < 4; ++_jj)                                     \
        (set)[_jj] = p4[(size_t)(c_) * (CH * CC / 4) + (jb + _jj) * 64 + lane]; \
    } while (0)

#define PITER(set, c_) do {                                               \
    float* _s = ring[(c_) & 3];                                           \
    _Pragma("unroll")                                                     \
    for (int _jj = 0; _jj < 4; ++_jj)                                     \
        *(f32x4*)&_s[((jb + _jj) * 64 + lane) * 4] = (set)[_jj];          \
    asm volatile("s_waitcnt lgkmcnt(0)" ::: "memory");                    \
    __builtin_amdgcn_sched_barrier(0);                                    \
    __builtin_amdgcn_s_barrier();      /* chunk c_ ready */               \
    __builtin_amdgcn_sched_barrier(0);                                    \
    if ((c_) + 3 < NC) LOADP(set, (c_) + 3);                              \
    } while (0)

        LOADP(RA, 0); LOADP(RB, 1); LOADP(RC, 2);
        PITER(RA, 0);  PITER(RB, 1);  PITER(RC, 2);
        PITER(RA, 3);  PITER(RB, 4);  PITER(RC, 5);
        PITER(RA, 6);  PITER(RB, 7);  PITER(RC, 8);
        PITER(RA, 9);  PITER(RB, 10); PITER(RC, 11);
        PITER(RA, 12); PITER(RB, 13); PITER(RC, 14);
        PITER(RA, 15);
#undef LOADP
#undef PITER
    } else {
        // ---------------- consumer (w = 0) ----------------
        int lab = CC - 1;                              // lanes >= LL carry blank
        if (lane < LL) lab = labels[b * LL + lane];
        const int labprev = __shfl_up(lab, 1);
        const float csf = ((lane > 0) && (lane < LL) && (lab != labprev)) ? 1.0f : 0.0f;

        float a0 = (lane == 0) ? 1.0f : 0.0f;          // uniform t=0 update -> alpha0
        float a1 = 0.0f;
        int lg = 0;

#define STEP(plv, pbv) do {                                               \
    const float _pp = dpp_mv<0x138>(a1);   /* wave_shr:1 -> a1[l-1] */    \
    const float _a0o = a0;                                                \
    a0 = (_a0o + _pp) * (pbv);                                            \
    a1 = (a1 + _a0o + csf * _pp) * (plv);                                 \
    } while (0)

#define RESCALE do {                                                      \
    float _m = fmaxf(a0, a1);                                             \
    _m = fmaxf(_m, dpp_mv<0x111>(_m));   /* row_shr:1 */                  \
    _m = fmaxf(_m, dpp_mv<0x112>(_m));   /* row_shr:2 */                  \
    _m = fmaxf(_m, dpp_mv<0x114>(_m));   /* row_shr:4 */                  \
    _m = fmaxf(_m, dpp_mv<0x118>(_m));   /* row_shr:8 */                  \
    _m = fmaxf(_m, dpp_mv<0x142>(_m));   /* row_bcast:15 */               \
    _m = fmaxf(_m, dpp_mv<0x143>(_m));   /* row_bcast:31 -> lane63 */     \
    const float _mm = rdlane(_m, 63);                                     \
    int _e; (void)frexpf(_mm, &_e);                                       \
    a0 = ldexpf(a0, -_e);                                                 \
    a1 = ldexpf(a1, -_e);                                                 \
    lg += _e;                                                             \
    } while (0)

#define CITER(c_) do {                                                    \
    __builtin_amdgcn_s_barrier();        /* chunk c_ is in LDS */         \
    __builtin_amdgcn_sched_barrier(0);                                    \
    const float* _s = ring[(c_) & 3];                                     \
    float _pl[CH], _pb[CH];                                               \
    _Pragma("unroll")                                                     \
    for (int _r = 0; _r < CH; ++_r) {                                     \
        _pl[_r] = _s[_r * CC + lab] + EPS;        /* per-lane column */   \
        _pb[_r] = _s[_r * CC + (CC - 1)] + EPS;   /* broadcast read */    \
    }                                                                     \
    _Pragma("unroll")                                                     \
    for (int _r = 0; _r < CH; ++_r) {                                     \
        STEP(_pl[_r], _pb[_r]);                                           \
        if ((_r & 7) == 7) RESCALE;                                       \
    } } while (0)

        CITER(0);  CITER(1);  CITER(2);  CITER(3);
        CITER(4);  CITER(5);  CITER(6);  CITER(7);
        CITER(8);  CITER(9);  CITER(10); CITER(11);
        CITER(12); CITER(13); CITER(14); CITER(15);

        // loss = -( log(alpha[95] + alpha[96]) + lg*ln2 )
        const float v95 = rdlane(a1, 47);
        const float v96 = rdlane(a0, 48);
        if (lane == 0) {
            const float s = fmaxf(v95 + v96, 1e-37f);
            out[b] = -(__logf(s) + (float)lg * 0.69314718056f);
        }
#undef STEP
#undef RESCALE
#undef CITER
    }
}

extern "C" void kernel_launch(void* const* d_in, const int* in_sizes, int n_in,
                              void* d_out, int out_size, void* d_ws, size_t ws_size,
                              hipStream_t stream) {
    const float* y = (const float*)d_in[0];
    const int* labels = (const int*)d_in[1];
    float* out = (float*)d_out;
    const int B = in_sizes[0] / (TT * CC);   // 1024
    ctc_fwd_v11<<<B, 192, 0, stream>>>(y, labels, out);
}

// Round 12
// 26.343 us; speedup vs baseline: 1.0244x; 1.0244x over previous
//
#include <hip/hip_runtime.h>

// CTC batch cost (Keras, blank=C-1). B=1024, T=256, C=128, L=48, S=97.
// R12: producer/consumer with PRODUCER-SIDE gather.
//   producer (wave1): streams rows coalesced (f32x2/lane, 3 chunks in flight),
//     gathers each consumer-lane's label prob in-register via 2x ds_bpermute +
//     select (R9-proven), writes ONLY the gathered 64 floats/row to LDS
//     ([row][lane], 2-way bank = free). 4 KB/slot, 4-slot ring, s_barrier.
//   consumer (wave0): conflict-free ds_read per row (own lane col + lane-63
//     broadcast for blank) + pure DP. DP/rescale numerics = R8-R11.

#define TT 256
#define CC 128
#define LL 48
#define CH 16          // rows per chunk
#define NC (TT / CH)   // 16 chunks

typedef float f32x2 __attribute__((ext_vector_type(2)));

template<int CTRL>
__device__ __forceinline__ float dpp_mv(float x) {
    union { float f; int i; } u, r;
    u.f = x;
    r.i = __builtin_amdgcn_update_dpp(0, u.i, CTRL, 0xF, 0xF, false); // invalid lanes -> 0
    return r.f;
}
__device__ __forceinline__ float rdlane(float x, int l) {
    union { float f; int i; } u, r;
    u.f = x;
    r.i = __builtin_amdgcn_readlane(u.i, l);
    return r.f;
}

__global__ __launch_bounds__(128) void ctc_fwd_v12(
    const float* __restrict__ y,       // [B, T, C]
    const int* __restrict__ labels,    // [B, L]
    float* __restrict__ out)           // [B]
{
    __shared__ float ring[4][CH * 64];         // 4 x 4 KB = 16 KB (gathered values)
    const int lane = threadIdx.x & 63;
    const int w = threadIdx.x >> 6;            // 0 = consumer, 1 = producer
    const int b = blockIdx.x;
    const float EPS = 1e-7f;

    // Both waves need the per-lane label (producer gathers with it).
    int lab = CC - 1;                          // lanes >= LL carry blank
    if (lane < LL) lab = labels[b * LL + lane];

    if (w == 1) {
        // ---------------- producer ----------------
        const int bidx = (lab >> 1) << 2;      // ds_bpermute byte index
        const bool odd = (lab & 1);
        const f32x2* p2 = (const f32x2*)(y + (size_t)b * TT * CC) + lane;
        f32x2 RA[CH], RB[CH], RC[CH];

#define LOADP(set, c_) do {                                               \
    _Pragma("unroll")                                                     \
    for (int _j = 0; _j < CH; ++_j)                                       \
        (set)[_j] = p2[(size_t)((c_) * CH + _j) * (CC / 2)];              \
    } while (0)

#define PITER(set, c_) do {                                               \
    float* _s = ring[(c_) & 3];                                           \
    _Pragma("unroll")                                                     \
    for (int _j = 0; _j < CH; ++_j) {                                     \
        const int _lo = __builtin_amdgcn_ds_bpermute(bidx, __float_as_int((set)[_j].x)); \
        const int _hi = __builtin_amdgcn_ds_bpermute(bidx, __float_as_int((set)[_j].y)); \
        _s[_j * 64 + lane] = __int_as_float(odd ? _hi : _lo);             \
    }                                                                     \
    asm volatile("s_waitcnt lgkmcnt(0)" ::: "memory");                    \
    __builtin_amdgcn_sched_barrier(0);                                    \
    __builtin_amdgcn_s_barrier();      /* chunk c_ ready */               \
    __builtin_amdgcn_sched_barrier(0);                                    \
    if ((c_) + 3 < NC) LOADP(set, (c_) + 3);                              \
    } while (0)

        LOADP(RA, 0); LOADP(RB, 1); LOADP(RC, 2);
        PITER(RA, 0);  PITER(RB, 1);  PITER(RC, 2);
        PITER(RA, 3);  PITER(RB, 4);  PITER(RC, 5);
        PITER(RA, 6);  PITER(RB, 7);  PITER(RC, 8);
        PITER(RA, 9);  PITER(RB, 10); PITER(RC, 11);
        PITER(RA, 12); PITER(RB, 13); PITER(RC, 14);
        PITER(RA, 15);
#undef LOADP
#undef PITER
    } else {
        // ---------------- consumer ----------------
        const int labprev = __shfl_up(lab, 1);
        const float csf = ((lane > 0) && (lane < LL) && (lab != labprev)) ? 1.0f : 0.0f;

        float a0 = (lane == 0) ? 1.0f : 0.0f;          // uniform t=0 update -> alpha0
        float a1 = 0.0f;
        int lg = 0;

#define STEP(plv, pbv) do {                                               \
    const float _pp = dpp_mv<0x138>(a1);   /* wave_shr:1 -> a1[l-1] */    \
    const float _a0o = a0;                                                \
    a0 = (_a0o + _pp) * (pbv);                                            \
    a1 = (a1 + _a0o + csf * _pp) * (plv);                                 \
    } while (0)

#define RESCALE do {                                                      \
    float _m = fmaxf(a0, a1);                                             \
    _m = fmaxf(_m, dpp_mv<0x111>(_m));   /* row_shr:1 */                  \
    _m = fmaxf(_m, dpp_mv<0x112>(_m));   /* row_shr:2 */                  \
    _m = fmaxf(_m, dpp_mv<0x114>(_m));   /* row_shr:4 */                  \
    _m = fmaxf(_m, dpp_mv<0x118>(_m));   /* row_shr:8 */                  \
    _m = fmaxf(_m, dpp_mv<0x142>(_m));   /* row_bcast:15 */               \
    _m = fmaxf(_m, dpp_mv<0x143>(_m));   /* row_bcast:31 -> lane63 */     \
    const float _mm = rdlane(_m, 63);                                     \
    int _e; (void)frexpf(_mm, &_e);                                       \
    a0 = ldexpf(a0, -_e);                                                 \
    a1 = ldexpf(a1, -_e);                                                 \
    lg += _e;                                                             \
    } while (0)

#define CITER(c_) do {                                                    \
    __builtin_amdgcn_s_barrier();        /* chunk c_ is in LDS */         \
    __builtin_amdgcn_sched_barrier(0);                                    \
    const float* _s = ring[(c_) & 3];                                     \
    float _pl[CH], _pb[CH];                                               \
    _Pragma("unroll")                                                     \
    for (int _r = 0; _r < CH; ++_r) {                                     \
        _pl[_r] = _s[_r * 64 + lane] + EPS;   /* conflict-free (2-way) */ \
        _pb[_r] = _s[_r * 64 + 63] + EPS;     /* broadcast (blank) */     \
    }                                                                     \
    _Pragma("unroll")                                                     \
    for (int _r = 0; _r < CH; ++_r) {                                     \
        STEP(_pl[_r], _pb[_r]);                                           \
        if ((_r & 7) == 7) RESCALE;                                       \
    } } while (0)

        CITER(0);  CITER(1);  CITER(2);  CITER(3);
        CITER(4);  CITER(5);  CITER(6);  CITER(7);
        CITER(8);  CITER(9);  CITER(10); CITER(11);
        CITER(12); CITER(13); CITER(14); CITER(15);

        // loss = -( log(alpha[95] + alpha[96]) + lg*ln2 )
        const float v95 = rdlane(a1, 47);
        const float v96 = rdlane(a0, 48);
        if (lane == 0) {
            const float s = fmaxf(v95 + v96, 1e-37f);
            out[b] = -(__logf(s) + (float)lg * 0.69314718056f);
        }
#undef STEP
#undef RESCALE
#undef CITER
    }
}

extern "C" void kernel_launch(void* const* d_in, const int* in_sizes, int n_in,
                              void* d_out, int out_size, void* d_ws, size_t ws_size,
                              hipStream_t stream) {
    const float* y = (const float*)d_in[0];
    const int* labels = (const int*)d_in[1];
    float* out = (float*)d_out;
    const int B = in_sizes[0] / (TT * CC);   // 1024
    ctc_fwd_v12<<<B, 128, 0, stream>>>(y, labels, out);
}

// Round 13
// 25.354 us; speedup vs baseline: 1.0643x; 1.0390x over previous
//
#include <hip/hip_runtime.h>

// CTC batch cost (Keras, blank=C-1). B=1024, T=256, C=128, L=48, S=97.
// R13 = R12 + NON-TEMPORAL producer loads (bypass L1 allocation; stream data
// is single-use). All other structure/numerics bit-identical to R12.
//   producer (wave1): NT f32x2 streaming loads, 3 chunks in flight,
//     in-register bpermute gather, writes gathered 64 floats/row to LDS ring.
//   consumer (wave0): conflict-free ds_read + pure DP (R8-R12 numerics).

#define TT 256
#define CC 128
#define LL 48
#define CH 16          // rows per chunk
#define NC (TT / CH)   // 16 chunks

typedef float f32x2 __attribute__((ext_vector_type(2)));

template<int CTRL>
__device__ __forceinline__ float dpp_mv(float x) {
    union { float f; int i; } u, r;
    u.f = x;
    r.i = __builtin_amdgcn_update_dpp(0, u.i, CTRL, 0xF, 0xF, false); // invalid lanes -> 0
    return r.f;
}
__device__ __forceinline__ float rdlane(float x, int l) {
    union { float f; int i; } u, r;
    u.f = x;
    r.i = __builtin_amdgcn_readlane(u.i, l);
    return r.f;
}

__global__ __launch_bounds__(128) void ctc_fwd_v13(
    const float* __restrict__ y,       // [B, T, C]
    const int* __restrict__ labels,    // [B, L]
    float* __restrict__ out)           // [B]
{
    __shared__ float ring[4][CH * 64];         // 4 x 4 KB (gathered values)
    const int lane = threadIdx.x & 63;
    const int w = threadIdx.x >> 6;            // 0 = consumer, 1 = producer
    const int b = blockIdx.x;
    const float EPS = 1e-7f;

    int lab = CC - 1;                          // lanes >= LL carry blank
    if (lane < LL) lab = labels[b * LL + lane];

    if (w == 1) {
        // ---------------- producer ----------------
        const int bidx = (lab >> 1) << 2;      // ds_bpermute byte index
        const bool odd = (lab & 1);
        const f32x2* p2 = (const f32x2*)(y + (size_t)b * TT * CC) + lane;
        f32x2 RA[CH], RB[CH], RC[CH];

#define LOADP(set, c_) do {                                               \
    _Pragma("unroll")                                                     \
    for (int _j = 0; _j < CH; ++_j)                                       \
        (set)[_j] = __builtin_nontemporal_load(                           \
            p2 + (size_t)((c_) * CH + _j) * (CC / 2));                    \
    } while (0)

#define PITER(set, c_) do {                                               \
    float* _s = ring[(c_) & 3];                                           \
    _Pragma("unroll")                                                     \
    for (int _j = 0; _j < CH; ++_j) {                                     \
        const int _lo = __builtin_amdgcn_ds_bpermute(bidx, __float_as_int((set)[_j].x)); \
        const int _hi = __builtin_amdgcn_ds_bpermute(bidx, __float_as_int((set)[_j].y)); \
        _s[_j * 64 + lane] = __int_as_float(odd ? _hi : _lo);             \
    }                                                                     \
    asm volatile("s_waitcnt lgkmcnt(0)" ::: "memory");                    \
    __builtin_amdgcn_sched_barrier(0);                                    \
    __builtin_amdgcn_s_barrier();      /* chunk c_ ready */               \
    __builtin_amdgcn_sched_barrier(0);                                    \
    if ((c_) + 3 < NC) LOADP(set, (c_) + 3);                              \
    } while (0)

        LOADP(RA, 0); LOADP(RB, 1); LOADP(RC, 2);
        PITER(RA, 0);  PITER(RB, 1);  PITER(RC, 2);
        PITER(RA, 3);  PITER(RB, 4);  PITER(RC, 5);
        PITER(RA, 6);  PITER(RB, 7);  PITER(RC, 8);
        PITER(RA, 9);  PITER(RB, 10); PITER(RC, 11);
        PITER(RA, 12); PITER(RB, 13); PITER(RC, 14);
        PITER(RA, 15);
#undef LOADP
#undef PITER
    } else {
        // ---------------- consumer ----------------
        const int labprev = __shfl_up(lab, 1);
        const float csf = ((lane > 0) && (lane < LL) && (lab != labprev)) ? 1.0f : 0.0f;

        float a0 = (lane == 0) ? 1.0f : 0.0f;          // uniform t=0 update -> alpha0
        float a1 = 0.0f;
        int lg = 0;

#define STEP(plv, pbv) do {                                               \
    const float _pp = dpp_mv<0x138>(a1);   /* wave_shr:1 -> a1[l-1] */    \
    const float _a0o = a0;                                                \
    a0 = (_a0o + _pp) * (pbv);                                            \
    a1 = (a1 + _a0o + csf * _pp) * (plv);                                 \
    } while (0)

#define RESCALE do {                                                      \
    float _m = fmaxf(a0, a1);                                             \
    _m = fmaxf(_m, dpp_mv<0x111>(_m));   /* row_shr:1 */                  \
    _m = fmaxf(_m, dpp_mv<0x112>(_m));   /* row_shr:2 */                  \
    _m = fmaxf(_m, dpp_mv<0x114>(_m));   /* row_shr:4 */                  \
    _m = fmaxf(_m, dpp_mv<0x118>(_m));   /* row_shr:8 */                  \
    _m = fmaxf(_m, dpp_mv<0x142>(_m));   /* row_bcast:15 */               \
    _m = fmaxf(_m, dpp_mv<0x143>(_m));   /* row_bcast:31 -> lane63 */     \
    const float _mm = rdlane(_m, 63);                                     \
    int _e; (void)frexpf(_mm, &_e);                                       \
    a0 = ldexpf(a0, -_e);                                                 \
    a1 = ldexpf(a1, -_e);                                                 \
    lg += _e;                                                             \
    } while (0)

#define CITER(c_) do {                                                    \
    __builtin_amdgcn_s_barrier();        /* chunk c_ is in LDS */         \
    __builtin_amdgcn_sched_barrier(0);                                    \
    const float* _s = ring[(c_) & 3];                                     \
    float _pl[CH], _pb[CH];                                               \
    _Pragma("unroll")                                                     \
    for (int _r = 0; _r < CH; ++_r) {                                     \
        _pl[_r] = _s[_r * 64 + lane] + EPS;   /* conflict-free (2-way) */ \
        _pb[_r] = _s[_r * 64 + 63] + EPS;     /* broadcast (blank) */     \
    }                                                                     \
    _Pragma("unroll")                                                     \
    for (int _r = 0; _r < CH; ++_r) {                                     \
        STEP(_pl[_r], _pb[_r]);                                           \
        if ((_r & 7) == 7) RESCALE;                                       \
    } } while (0)

        CITER(0);  CITER(1);  CITER(2);  CITER(3);
        CITER(4);  CITER(5);  CITER(6);  CITER(7);
        CITER(8);  CITER(9);  CITER(10); CITER(11);
        CITER(12); CITER(13); CITER(14); CITER(15);

        // loss = -( log(alpha[95] + alpha[96]) + lg*ln2 )
        const float v95 = rdlane(a1, 47);
        const float v96 = rdlane(a0, 48);
        if (lane == 0) {
            const float s = fmaxf(v95 + v96, 1e-37f);
            out[b] = -(__logf(s) + (float)lg * 0.69314718056f);
        }
#undef STEP
#undef RESCALE
#undef CITER
    }
}

extern "C" void kernel_launch(void* const* d_in, const int* in_sizes, int n_in,
                              void* d_out, int out_size, void* d_ws, size_t ws_size,
                              hipStream_t stream) {
    const float* y = (const float*)d_in[0];
    const int* labels = (const int*)d_in[1];
    float* out = (float*)d_out;
    const int B = in_sizes[0] / (TT * CC);   // 1024
    ctc_fwd_v13<<<B, 128, 0, stream>>>(y, labels, out);
}